// Round 1
// baseline (363.293 us; speedup 1.0000x reference)
//
#include <hip/hip_runtime.h>
#include <cstddef>

#define HIDDEN 128
#define BN_EPS 1e-5f
#define SCAN_CHUNK 1024  // cnt elements per scan block
#define KS 136           // GEMM LDS row stride (ushort): 272B = 17*16B -> aligned b128

typedef __attribute__((ext_vector_type(8))) short short8;    // 8 bf16 (4 VGPRs)
typedef __attribute__((ext_vector_type(4))) float float4v;   // MFMA acc
typedef __attribute__((ext_vector_type(4))) unsigned uint4v;

// RNE float->bf16 (manual, exact for non-NaN)
__device__ inline unsigned bf16_rne(float f) {
    unsigned u = __float_as_uint(f);
    return (u + 0x7fff + ((u >> 16) & 1)) >> 16;
}
__device__ inline unsigned pack2_bf16(float a, float b) {
    return bf16_rne(a) | (bf16_rne(b) << 16);
}

// ---------- K1: in-degree histogram (int4-vectorized col reads) ----------
__global__ void k_count(const int* __restrict__ col, int* __restrict__ cnt, int E) {
    int base = (blockIdx.x * 256 + threadIdx.x) * 4;
    if (base + 3 < E) {
        int4 c = *(const int4*)&col[base];
        atomicAdd(&cnt[c.x], 1);
        atomicAdd(&cnt[c.y], 1);
        atomicAdd(&cnt[c.z], 1);
        atomicAdd(&cnt[c.w], 1);
    } else {
        for (int k = 0; k < 4; ++k) {
            int e = base + k;
            if (e < E) atomicAdd(&cnt[col[e]], 1);
        }
    }
}

// ---------- K2: fused CSR-build scan (decoupled lookback, 1 dispatch) ----------
__global__ __launch_bounds__(256) void k_csr(int* __restrict__ cnt,
                                             unsigned long long* __restrict__ flags,
                                             int* __restrict__ off,
                                             float* __restrict__ dinv, int N, int NB) {
    __shared__ int s[256];
    __shared__ int sbase;
    int tid = threadIdx.x;
    int b = blockIdx.x;
    int base = b * SCAN_CHUNK;
    int c[4];
    int t = 0;
#pragma unroll
    for (int k = 0; k < 4; ++k) {
        int idx = base + tid * 4 + k;
        c[k] = (idx < N) ? cnt[idx] : 0;
        t += c[k];
    }
    s[tid] = t;
    __syncthreads();
    for (int o = 1; o < 256; o <<= 1) {
        int v = (tid >= o) ? s[tid - o] : 0;
        __syncthreads();
        s[tid] += v;
        __syncthreads();
    }
    int incl = s[tid];
    int total = s[255];

    if (b == 0) {
        if (tid == 0) {
            sbase = 0;
            atomicExch(&flags[0], (2ULL << 32) | (unsigned)total);
        }
    } else {
        if (tid == 0) atomicExch(&flags[b], (1ULL << 32) | (unsigned)total);
        if (tid < 64) {  // wave-0 parallel lookback
            int excl = 0;
            int look = b - 1;
            while (true) {
                int idx = look - tid;
                unsigned long long v = 0;
                if (idx >= 0) {
                    do { v = atomicAdd(&flags[idx], 0ULL); } while ((v >> 32) == 0ULL);
                }
                int st = (int)(v >> 32);
                unsigned long long ball = __ballot(idx >= 0 && st == 2);
                int firstInc = ball ? (__ffsll(ball) - 1) : 64;
                int val = (idx >= 0 && tid <= firstInc) ? (int)(v & 0xffffffffULL) : 0;
#pragma unroll
                for (int o = 32; o > 0; o >>= 1) val += __shfl_down(val, o);
                if (tid == 0) excl += val;
                if (firstInc < 64 || look - 64 < 0) break;
                look -= 64;
            }
            if (tid == 0) {
                sbase = excl;
                atomicExch(&flags[b], (2ULL << 32) | (unsigned)(excl + total));
            }
        }
    }
    __syncthreads();

    int run = sbase + incl - t;
#pragma unroll
    for (int k = 0; k < 4; ++k) {
        int idx = base + tid * 4 + k;
        if (idx < N) {
            off[idx] = run;
            run += c[k];
            dinv[idx] = rsqrtf((float)(c[k] + 1));  // deg includes self-loop
            cnt[idx] = 0;                           // reused as cursor in k_place
        }
    }
    if (b == NB - 1 && tid == 255) off[N] = sbase + incl;
}

// ---------- K3: xu(bf16) = dinv .* (x @ W) via bf16 MFMA ----------
// 128x128 tile/block, K=128 staged once as bf16 in LDS. Epilogue bounces C
// through lA -> fully-coalesced uint4 stores. (No NT: it regressed in R8.)
__global__ __launch_bounds__(256) void k_gemm(const float* __restrict__ x,
                                              const float* __restrict__ W,
                                              const float* __restrict__ dinv,
                                              unsigned short* __restrict__ xus, int N) {
    __shared__ unsigned short lA[128 * KS];  // [m][k] bf16, reused for C bounce
    __shared__ unsigned short lB[128 * KS];  // [n][k] bf16 (W transposed)
    int tid = threadIdx.x;
    int row0 = blockIdx.x * 128;
    int wv = tid >> 6;
    int lane = tid & 63;
    int l15 = lane & 15;
    int lq = lane >> 4;  // 0..3

    for (int it = 0; it < 16; ++it) {
        int idx4 = it * 256 + tid;
        int m = idx4 >> 5, c4 = idx4 & 31;
        int grow = row0 + m;
        float4 v = make_float4(0.f, 0.f, 0.f, 0.f);
        if (grow < N) v = ((const float4*)x)[(size_t)grow * 32 + c4];
        uint2 pk;
        pk.x = pack2_bf16(v.x, v.y);
        pk.y = pack2_bf16(v.z, v.w);
        *(uint2*)&lA[m * KS + c4 * 4] = pk;
    }
    for (int it = 0; it < 16; ++it) {
        int idx4 = it * 256 + tid;               // 4096 float4
        int k = idx4 >> 5, n4 = idx4 & 31;       // n = 4*n4
        float4 v = ((const float4*)W)[(size_t)k * 32 + n4];
        int n = n4 * 4;
        lB[(n + 0) * KS + k] = (unsigned short)bf16_rne(v.x);
        lB[(n + 1) * KS + k] = (unsigned short)bf16_rne(v.y);
        lB[(n + 2) * KS + k] = (unsigned short)bf16_rne(v.z);
        lB[(n + 3) * KS + k] = (unsigned short)bf16_rne(v.w);
    }
    __syncthreads();

    float4v acc[2][8];
#pragma unroll
    for (int i = 0; i < 2; ++i)
#pragma unroll
        for (int j = 0; j < 8; ++j) acc[i][j] = (float4v){0.f, 0.f, 0.f, 0.f};

#pragma unroll
    for (int kc = 0; kc < 4; ++kc) {
        int ko = kc * 32 + lq * 8;
        short8 a0 = *(const short8*)&lA[(wv * 32 + l15) * KS + ko];
        short8 a1 = *(const short8*)&lA[(wv * 32 + 16 + l15) * KS + ko];
        short8 bfr[8];
#pragma unroll
        for (int nt = 0; nt < 8; ++nt)
            bfr[nt] = *(const short8*)&lB[(nt * 16 + l15) * KS + ko];
#pragma unroll
        for (int nt = 0; nt < 8; ++nt) {
            acc[0][nt] = __builtin_amdgcn_mfma_f32_16x16x32_bf16(a0, bfr[nt], acc[0][nt], 0, 0, 0);
            acc[1][nt] = __builtin_amdgcn_mfma_f32_16x16x32_bf16(a1, bfr[nt], acc[1][nt], 0, 0, 0);
        }
    }

    __syncthreads();  // all lA fragment reads done before C bounce

    // bounce C into lA as bf16 (scattered b16 LDS writes, cheap)
#pragma unroll
    for (int mt = 0; mt < 2; ++mt) {
#pragma unroll
        for (int reg = 0; reg < 4; ++reg) {
            int rl = wv * 32 + mt * 16 + lq * 4 + reg;  // local row
            int r = row0 + rl;
            float d = (r < N) ? dinv[r] : 0.f;
#pragma unroll
            for (int nt = 0; nt < 8; ++nt)
                lA[rl * KS + nt * 16 + l15] = (unsigned short)bf16_rne(acc[mt][nt][reg] * d);
        }
    }
    __syncthreads();

    // coalesced store: 128 rows x 16 uint4 (256B/row)
    for (int it = 0; it < 8; ++it) {
        int idx = it * 256 + tid;
        int r = idx >> 4, c16 = idx & 15;
        int grow = row0 + r;
        if (grow < N) {
            uint4v v = *(const uint4v*)&lA[r * KS + c16 * 8];
            *((uint4v*)(xus + (size_t)grow * 128) + c16) = v;
        }
    }
}

// ---------- K4: counting-sort edges by target (4 edges/thread, int4) ----------
__global__ void k_place(const int* __restrict__ row, const int* __restrict__ col,
                        const int* __restrict__ off, int* __restrict__ cur,
                        int* __restrict__ srcs, int E) {
    int base = (blockIdx.x * 256 + threadIdx.x) * 4;
    if (base + 3 < E) {
        int4 c = *(const int4*)&col[base];
        int4 r = *(const int4*)&row[base];
        int p0 = atomicAdd(&cur[c.x], 1);
        int p1 = atomicAdd(&cur[c.y], 1);
        int p2 = atomicAdd(&cur[c.z], 1);
        int p3 = atomicAdd(&cur[c.w], 1);
        srcs[off[c.x] + p0] = r.x;
        srcs[off[c.y] + p1] = r.y;
        srcs[off[c.z] + p2] = r.z;
        srcs[off[c.w] + p3] = r.w;
    } else {
        for (int k = 0; k < 4; ++k) {
            int e = base + k;
            if (e < E) {
                int c = col[e];
                int p = atomicAdd(&cur[c], 1);
                srcs[off[c] + p] = row[e];
            }
        }
    }
}

// ---------- K5: gather-aggregate, flat edge-stream version ----------
// Waves own contiguous EDGE ranges (edge-balanced via binary search on off);
// nodes wholly owned -> no atomics. srcs stream is contiguous, so the gather
// pipeline (2x8 double-buffered) never drains at node boundaries. Node
// finalize (self-loop + bias + bf16 store + BN stats) handled inline when the
// stream crosses off[i+1].
#define LOADC(U, base_) do {                                                   \
    int _b = (base_);                                                          \
    int _s0 = (_b + 0 < jend) ? srcs[_b + 0] : 0;                              \
    int _s1 = (_b + 1 < jend) ? srcs[_b + 1] : 0;                              \
    int _s2 = (_b + 2 < jend) ? srcs[_b + 2] : 0;                              \
    int _s3 = (_b + 3 < jend) ? srcs[_b + 3] : 0;                              \
    int _s4 = (_b + 4 < jend) ? srcs[_b + 4] : 0;                              \
    int _s5 = (_b + 5 < jend) ? srcs[_b + 5] : 0;                              \
    int _s6 = (_b + 6 < jend) ? srcs[_b + 6] : 0;                              \
    int _s7 = (_b + 7 < jend) ? srcs[_b + 7] : 0;                              \
    U##0 = xu[(size_t)_s0 * 64 + lane];                                        \
    U##1 = xu[(size_t)_s1 * 64 + lane];                                        \
    U##2 = xu[(size_t)_s2 * 64 + lane];                                        \
    U##3 = xu[(size_t)_s3 * 64 + lane];                                        \
    U##4 = xu[(size_t)_s4 * 64 + lane];                                        \
    U##5 = xu[(size_t)_s5 * 64 + lane];                                        \
    U##6 = xu[(size_t)_s6 * 64 + lane];                                        \
    U##7 = xu[(size_t)_s7 * 64 + lane];                                        \
} while (0)

#define FIN() do {                                                             \
    float _sx = __uint_as_float(uself << 16);                                  \
    float _sy = __uint_as_float(uself & 0xffff0000u);                          \
    float _ox = fmaf(ax + _sx, di, bb.x);                                      \
    float _oy = fmaf(ay + _sy, di, bb.y);                                      \
    agg[(size_t)i * 64 + lane] = pack2_bf16(_ox, _oy);                         \
    s.x += _ox; s.y += _oy;                                                    \
    qq.x = fmaf(_ox, _ox, qq.x); qq.y = fmaf(_oy, _oy, qq.y);                  \
    ++i;                                                                       \
    if (i < i_end) {                                                           \
        cur_end = off[i + 1];                                                  \
        di = dinv[i];                                                          \
        uself = xu[(size_t)i * 64 + lane];                                     \
    } else {                                                                   \
        cur_end = 0x7fffffff;                                                  \
    }                                                                          \
    ax = 0.f; ay = 0.f;                                                        \
} while (0)

#define CONS(U, k) do {                                                        \
    int _p = jc + k;                                                           \
    if (_p < jend) {                                                           \
        while (_p == cur_end) FIN();                                           \
        ax += __uint_as_float(U##k << 16);                                     \
        ay += __uint_as_float(U##k & 0xffff0000u);                             \
    }                                                                          \
} while (0)

__global__ __launch_bounds__(256) void k_gather(const unsigned* __restrict__ xu,
                                                const float* __restrict__ dinv,
                                                const int* __restrict__ off,
                                                const int* __restrict__ srcs,
                                                const float* __restrict__ b,
                                                unsigned* __restrict__ agg,
                                                float* __restrict__ bn, int N, int E) {
    int tid = threadIdx.x;
    int lane = tid & 63;
    int w = (blockIdx.x * 256 + tid) >> 6;
    int nw = (gridDim.x * 256) >> 6;
    float2 bb = ((const float2*)b)[lane];
    float2 s = make_float2(0.f, 0.f), qq = make_float2(0.f, 0.f);

    int EPW = (E + nw - 1) / nw;
    if (EPW < 1) EPW = 1;
    int E0 = w * EPW;
    int E1 = E0 + EPW;

    // node i is owned by the window containing off[i]; last window extends to N
    int i_start, i_end;
    {
        int lo = 0, hi = N;
        while (lo < hi) { int m = (lo + hi) >> 1; if (off[m] < E0) lo = m + 1; else hi = m; }
        i_start = lo;
        if (E1 > E) {
            i_end = N;
        } else {
            lo = i_start; hi = N;
            while (lo < hi) { int m = (lo + hi) >> 1; if (off[m] < E1) lo = m + 1; else hi = m; }
            i_end = lo;
        }
    }

    if (i_start < i_end) {
        int i = i_start;
        int jend = off[i_end];
        int jc = off[i];
        int cur_end = off[i + 1];
        float di = dinv[i];
        unsigned uself = xu[(size_t)i * 64 + lane];
        float ax = 0.f, ay = 0.f;

        unsigned uA0, uA1, uA2, uA3, uA4, uA5, uA6, uA7;
        unsigned uB0, uB1, uB2, uB3, uB4, uB5, uB6, uB7;
        if (jc < jend) {
            LOADC(uA, jc);
            LOADC(uB, jc + 8);
            int jl = jc + 16;
            while (true) {
                CONS(uA, 0); CONS(uA, 1); CONS(uA, 2); CONS(uA, 3);
                CONS(uA, 4); CONS(uA, 5); CONS(uA, 6); CONS(uA, 7);
                LOADC(uA, jl); jl += 8; jc += 8;
                if (jc >= jend) break;
                CONS(uB, 0); CONS(uB, 1); CONS(uB, 2); CONS(uB, 3);
                CONS(uB, 4); CONS(uB, 5); CONS(uB, 6); CONS(uB, 7);
                LOADC(uB, jl); jl += 8; jc += 8;
                if (jc >= jend) break;
            }
        }
        while (i < i_end) FIN();  // last node + trailing zero-degree nodes
    }

    __shared__ float ssum[HIDDEN];
    __shared__ float ssq[HIDDEN];
    if (tid < HIDDEN) { ssum[tid] = 0.f; ssq[tid] = 0.f; }
    __syncthreads();
    atomicAdd(&ssum[2 * lane],     s.x);
    atomicAdd(&ssum[2 * lane + 1], s.y);
    atomicAdd(&ssq[2 * lane],      qq.x);
    atomicAdd(&ssq[2 * lane + 1],  qq.y);
    __syncthreads();
    if (tid < HIDDEN) {
        atomicAdd(&bn[tid],          ssum[tid]);
        atomicAdd(&bn[HIDDEN + tid], ssq[tid]);
    }
}

// ---------- K6: BN normalize + gamma/beta + ReLU: bf16 agg -> fp32 out ----------
__global__ __launch_bounds__(256) void k_apply(const unsigned* __restrict__ agg,
                                               float* __restrict__ out,
                                               const float* __restrict__ bn,
                                               const float* __restrict__ gamma,
                                               const float* __restrict__ beta,
                                               int total8, float invN) {
    __shared__ float sc[HIDDEN], sh[HIDDEN];
    int tid = threadIdx.x;
    if (tid < HIDDEN) {
        float mean = bn[tid] * invN;
        float var = bn[HIDDEN + tid] * invN - mean * mean;
        float inv = rsqrtf(var + BN_EPS);
        float g = gamma[tid] * inv;
        sc[tid] = g;
        sh[tid] = beta[tid] - mean * g;
    }
    __syncthreads();
    int idx = blockIdx.x * 256 + tid;  // one uint2 = 4 cols
    if (idx < total8) {
        uint2 u = ((const uint2*)agg)[idx];
        int c = (idx & 31) * 4;
        float4 v;
        v.x = __uint_as_float(u.x << 16);
        v.y = __uint_as_float(u.x & 0xffff0000u);
        v.z = __uint_as_float(u.y << 16);
        v.w = __uint_as_float(u.y & 0xffff0000u);
        v.x = fmaxf(fmaf(v.x, sc[c],     sh[c]),     0.f);
        v.y = fmaxf(fmaf(v.y, sc[c + 1], sh[c + 1]), 0.f);
        v.z = fmaxf(fmaf(v.z, sc[c + 2], sh[c + 2]), 0.f);
        v.w = fmaxf(fmaf(v.w, sc[c + 3], sh[c + 3]), 0.f);
        ((float4*)out)[idx] = v;
    }
}

extern "C" void kernel_launch(void* const* d_in, const int* in_sizes, int n_in,
                              void* d_out, int out_size, void* d_ws, size_t ws_size,
                              hipStream_t stream) {
    const float* x     = (const float*)d_in[0];
    const int*   edges = (const int*)d_in[1];   // [2, E] int32 (JAX x64-off)
    const float* W     = (const float*)d_in[2];
    const float* b     = (const float*)d_in[3];
    const float* gamma = (const float*)d_in[4];
    const float* beta  = (const float*)d_in[5];
    float* out = (float*)d_out;

    int N = in_sizes[0] / HIDDEN;
    int E = in_sizes[1] / 2;
    const int* row = edges;      // sources
    const int* col = edges + E;  // targets

    int NB = (N + SCAN_CHUNK - 1) / SCAN_CHUNK;

    // workspace carve (~58 MB). Zeroed region contiguous: cnt | flags | bn.
    char* p = (char*)d_ws;
    unsigned* xu  = (unsigned*)p; p += (size_t)N * 64 * sizeof(unsigned);  // xw bf16
    unsigned* agg = (unsigned*)p; p += (size_t)N * 64 * sizeof(unsigned);  // agg bf16
    float* dinv   = (float*)p; p += (size_t)N * sizeof(float);
    int*   cnt    = (int*)p;   p += (size_t)N * sizeof(int);               // zeroed
    unsigned long long* flags = (unsigned long long*)p;
    p += (size_t)NB * sizeof(unsigned long long);                          // zeroed
    float* bn     = (float*)p; p += 256 * sizeof(float);                   // zeroed
    int*   off    = (int*)p;   p += ((size_t)N + 4) * sizeof(int);
    int*   srcs   = (int*)p;   p += (size_t)E * sizeof(int);

    size_t zbytes = (size_t)N * sizeof(int) + (size_t)NB * sizeof(unsigned long long)
                  + 256 * sizeof(float);

    dim3 blk(256);
    hipMemsetAsync(cnt, 0, zbytes, stream);
    k_count<<<dim3((E + 1023) / 1024), blk, 0, stream>>>(col, cnt, E);
    k_csr<<<dim3(NB), blk, 0, stream>>>(cnt, flags, off, dinv, N, NB);
    k_gemm<<<dim3((N + 127) / 128), blk, 0, stream>>>(x, W, dinv, (unsigned short*)xu, N);
    k_place<<<dim3((E + 1023) / 1024), blk, 0, stream>>>(row, col, off, cnt, srcs, E);
    k_gather<<<dim3(2048), blk, 0, stream>>>(xu, dinv, off, srcs, b, agg, bn, N, E);
    int total8 = N * 32;  // uint2 groups (4 cols each)
    k_apply<<<dim3((total8 + 255) / 256), blk, 0, stream>>>(agg, out, bn, gamma, beta,
                                                            total8, 1.0f / (float)N);
}

// Round 2
// 330.824 us; speedup vs baseline: 1.0981x; 1.0981x over previous
//
#include <hip/hip_runtime.h>
#include <cstddef>

#define HIDDEN 128
#define BN_EPS 1e-5f
#define SCAN_CHUNK 1024  // cnt elements per scan block
#define KS 136           // GEMM LDS row stride (ushort): 272B = 17*16B -> aligned b128

typedef __attribute__((ext_vector_type(8))) short short8;    // 8 bf16 (4 VGPRs)
typedef __attribute__((ext_vector_type(4))) float float4v;   // MFMA acc
typedef __attribute__((ext_vector_type(4))) unsigned uint4v;

// RNE float->bf16 (manual, exact for non-NaN)
__device__ inline unsigned bf16_rne(float f) {
    unsigned u = __float_as_uint(f);
    return (u + 0x7fff + ((u >> 16) & 1)) >> 16;
}
__device__ inline unsigned pack2_bf16(float a, float b) {
    return bf16_rne(a) | (bf16_rne(b) << 16);
}

// ---------- K1: in-degree histogram (int4-vectorized col reads) ----------
__global__ void k_count(const int* __restrict__ col, int* __restrict__ cnt, int E) {
    int base = (blockIdx.x * 256 + threadIdx.x) * 4;
    if (base + 3 < E) {
        int4 c = *(const int4*)&col[base];
        atomicAdd(&cnt[c.x], 1);
        atomicAdd(&cnt[c.y], 1);
        atomicAdd(&cnt[c.z], 1);
        atomicAdd(&cnt[c.w], 1);
    } else {
        for (int k = 0; k < 4; ++k) {
            int e = base + k;
            if (e < E) atomicAdd(&cnt[col[e]], 1);
        }
    }
}

// ---------- K2: fused CSR-build scan (decoupled lookback, 1 dispatch) ----------
__global__ __launch_bounds__(256) void k_csr(int* __restrict__ cnt,
                                             unsigned long long* __restrict__ flags,
                                             int* __restrict__ off,
                                             float* __restrict__ dinv, int N, int NB) {
    __shared__ int s[256];
    __shared__ int sbase;
    int tid = threadIdx.x;
    int b = blockIdx.x;
    int base = b * SCAN_CHUNK;
    int c[4];
    int t = 0;
#pragma unroll
    for (int k = 0; k < 4; ++k) {
        int idx = base + tid * 4 + k;
        c[k] = (idx < N) ? cnt[idx] : 0;
        t += c[k];
    }
    s[tid] = t;
    __syncthreads();
    for (int o = 1; o < 256; o <<= 1) {
        int v = (tid >= o) ? s[tid - o] : 0;
        __syncthreads();
        s[tid] += v;
        __syncthreads();
    }
    int incl = s[tid];
    int total = s[255];

    if (b == 0) {
        if (tid == 0) {
            sbase = 0;
            atomicExch(&flags[0], (2ULL << 32) | (unsigned)total);
        }
    } else {
        if (tid == 0) atomicExch(&flags[b], (1ULL << 32) | (unsigned)total);
        if (tid < 64) {  // wave-0 parallel lookback
            int excl = 0;
            int look = b - 1;
            while (true) {
                int idx = look - tid;
                unsigned long long v = 0;
                if (idx >= 0) {
                    do { v = atomicAdd(&flags[idx], 0ULL); } while ((v >> 32) == 0ULL);
                }
                int st = (int)(v >> 32);
                unsigned long long ball = __ballot(idx >= 0 && st == 2);
                int firstInc = ball ? (__ffsll(ball) - 1) : 64;
                int val = (idx >= 0 && tid <= firstInc) ? (int)(v & 0xffffffffULL) : 0;
#pragma unroll
                for (int o = 32; o > 0; o >>= 1) val += __shfl_down(val, o);
                if (tid == 0) excl += val;
                if (firstInc < 64 || look - 64 < 0) break;
                look -= 64;
            }
            if (tid == 0) {
                sbase = excl;
                atomicExch(&flags[b], (2ULL << 32) | (unsigned)(excl + total));
            }
        }
    }
    __syncthreads();

    int run = sbase + incl - t;
#pragma unroll
    for (int k = 0; k < 4; ++k) {
        int idx = base + tid * 4 + k;
        if (idx < N) {
            off[idx] = run;
            run += c[k];
            dinv[idx] = rsqrtf((float)(c[k] + 1));  // deg includes self-loop
            cnt[idx] = 0;                           // reused as cursor in k_place
        }
    }
    if (b == NB - 1 && tid == 255) off[N] = sbase + incl;
}

// ---------- K3: xu(bf16) = dinv .* (x @ W) via bf16 MFMA ----------
// 128x128 tile/block, K=128 staged once as bf16 in LDS. Epilogue bounces C
// through lA -> fully-coalesced uint4 stores. (No NT: it regressed in R8.)
__global__ __launch_bounds__(256) void k_gemm(const float* __restrict__ x,
                                              const float* __restrict__ W,
                                              const float* __restrict__ dinv,
                                              unsigned short* __restrict__ xus, int N) {
    __shared__ unsigned short lA[128 * KS];  // [m][k] bf16, reused for C bounce
    __shared__ unsigned short lB[128 * KS];  // [n][k] bf16 (W transposed)
    int tid = threadIdx.x;
    int row0 = blockIdx.x * 128;
    int wv = tid >> 6;
    int lane = tid & 63;
    int l15 = lane & 15;
    int lq = lane >> 4;  // 0..3

    for (int it = 0; it < 16; ++it) {
        int idx4 = it * 256 + tid;
        int m = idx4 >> 5, c4 = idx4 & 31;
        int grow = row0 + m;
        float4 v = make_float4(0.f, 0.f, 0.f, 0.f);
        if (grow < N) v = ((const float4*)x)[(size_t)grow * 32 + c4];
        uint2 pk;
        pk.x = pack2_bf16(v.x, v.y);
        pk.y = pack2_bf16(v.z, v.w);
        *(uint2*)&lA[m * KS + c4 * 4] = pk;
    }
    for (int it = 0; it < 16; ++it) {
        int idx4 = it * 256 + tid;               // 4096 float4
        int k = idx4 >> 5, n4 = idx4 & 31;       // n = 4*n4
        float4 v = ((const float4*)W)[(size_t)k * 32 + n4];
        int n = n4 * 4;
        lB[(n + 0) * KS + k] = (unsigned short)bf16_rne(v.x);
        lB[(n + 1) * KS + k] = (unsigned short)bf16_rne(v.y);
        lB[(n + 2) * KS + k] = (unsigned short)bf16_rne(v.z);
        lB[(n + 3) * KS + k] = (unsigned short)bf16_rne(v.w);
    }
    __syncthreads();

    float4v acc[2][8];
#pragma unroll
    for (int i = 0; i < 2; ++i)
#pragma unroll
        for (int j = 0; j < 8; ++j) acc[i][j] = (float4v){0.f, 0.f, 0.f, 0.f};

#pragma unroll
    for (int kc = 0; kc < 4; ++kc) {
        int ko = kc * 32 + lq * 8;
        short8 a0 = *(const short8*)&lA[(wv * 32 + l15) * KS + ko];
        short8 a1 = *(const short8*)&lA[(wv * 32 + 16 + l15) * KS + ko];
        short8 bfr[8];
#pragma unroll
        for (int nt = 0; nt < 8; ++nt)
            bfr[nt] = *(const short8*)&lB[(nt * 16 + l15) * KS + ko];
#pragma unroll
        for (int nt = 0; nt < 8; ++nt) {
            acc[0][nt] = __builtin_amdgcn_mfma_f32_16x16x32_bf16(a0, bfr[nt], acc[0][nt], 0, 0, 0);
            acc[1][nt] = __builtin_amdgcn_mfma_f32_16x16x32_bf16(a1, bfr[nt], acc[1][nt], 0, 0, 0);
        }
    }

    __syncthreads();  // all lA fragment reads done before C bounce

    // bounce C into lA as bf16 (scattered b16 LDS writes, cheap)
#pragma unroll
    for (int mt = 0; mt < 2; ++mt) {
#pragma unroll
        for (int reg = 0; reg < 4; ++reg) {
            int rl = wv * 32 + mt * 16 + lq * 4 + reg;  // local row
            int r = row0 + rl;
            float d = (r < N) ? dinv[r] : 0.f;
#pragma unroll
            for (int nt = 0; nt < 8; ++nt)
                lA[rl * KS + nt * 16 + l15] = (unsigned short)bf16_rne(acc[mt][nt][reg] * d);
        }
    }
    __syncthreads();

    // coalesced store: 128 rows x 16 uint4 (256B/row)
    for (int it = 0; it < 8; ++it) {
        int idx = it * 256 + tid;
        int r = idx >> 4, c16 = idx & 15;
        int grow = row0 + r;
        if (grow < N) {
            uint4v v = *(const uint4v*)&lA[r * KS + c16 * 8];
            *((uint4v*)(xus + (size_t)grow * 128) + c16) = v;
        }
    }
}

// ---------- K4: counting-sort edges by target (4 edges/thread, int4) ----------
__global__ void k_place(const int* __restrict__ row, const int* __restrict__ col,
                        const int* __restrict__ off, int* __restrict__ cur,
                        int* __restrict__ srcs, int E) {
    int base = (blockIdx.x * 256 + threadIdx.x) * 4;
    if (base + 3 < E) {
        int4 c = *(const int4*)&col[base];
        int4 r = *(const int4*)&row[base];
        int p0 = atomicAdd(&cur[c.x], 1);
        int p1 = atomicAdd(&cur[c.y], 1);
        int p2 = atomicAdd(&cur[c.z], 1);
        int p3 = atomicAdd(&cur[c.w], 1);
        srcs[off[c.x] + p0] = r.x;
        srcs[off[c.y] + p1] = r.y;
        srcs[off[c.z] + p2] = r.z;
        srcs[off[c.w] + p3] = r.w;
    } else {
        for (int k = 0; k < 4; ++k) {
            int e = base + k;
            if (e < E) {
                int c = col[e];
                int p = atomicAdd(&cur[c], 1);
                srcs[off[c] + p] = row[e];
            }
        }
    }
}

// ---------- K5: gather-aggregate (v0 structure + batched tail + scalar srcs
//             + node-level metadata prefetch) + BN stats ----------
// Wave w owns nodes w, w+nw, ... (interleaved). Per node:
//   - metadata (off pair, dinv, self-row) was issued during the PREVIOUS node
//   - full 8-edge chunks: 8 scalar srcs loads -> 8 gathers, batch-issued
//   - remainder (1..7 edges): ONE predicated batch (clamped scalar index,
//     select-to-zero after load) -> no serial dependent gathers anywhere
__global__ __launch_bounds__(256) void k_gather(const unsigned* __restrict__ xu,
                                                const float* __restrict__ dinv,
                                                const int* __restrict__ off,
                                                const int* __restrict__ srcs,
                                                const float* __restrict__ b,
                                                unsigned* __restrict__ agg,
                                                float* __restrict__ bn, int N) {
    int tid = threadIdx.x;
    int lane = tid & 63;
    int w = (blockIdx.x * 256 + tid) >> 6;
    int nw = (gridDim.x * 256) >> 6;
    float2 bb = ((const float2*)b)[lane];
    float2 s = make_float2(0.f, 0.f), qq = make_float2(0.f, 0.f);

    int i = w;
    int e0 = 0, e1 = 0;
    float di = 0.f;
    unsigned uself = 0;
    if (i < N) {
        e0 = off[i];
        e1 = off[i + 1];
        di = dinv[i];
        uself = xu[(size_t)i * 64 + lane];
    }

    while (i < N) {
        // issue next node's metadata + self-row NOW; consumed next iteration
        int inext = i + nw;
        int ne0 = 0, ne1 = 0;
        float ndi = 0.f;
        unsigned nself = 0;
        if (inext < N) {
            ne0 = off[inext];
            ne1 = off[inext + 1];
            ndi = dinv[inext];
            nself = xu[(size_t)inext * 64 + lane];
        }

        // self-loop row was loaded a full node ago -> no wait here
        float ax = __uint_as_float(uself << 16);
        float ay = __uint_as_float(uself & 0xffff0000u);

        int j = __builtin_amdgcn_readfirstlane(e0);
        int jend = __builtin_amdgcn_readfirstlane(e1);

        // full 8-edge chunks: scalar index loads, batch-issued gathers
        for (; j + 8 <= jend; j += 8) {
            int r0 = srcs[j + 0], r1 = srcs[j + 1], r2 = srcs[j + 2], r3 = srcs[j + 3];
            int r4 = srcs[j + 4], r5 = srcs[j + 5], r6 = srcs[j + 6], r7 = srcs[j + 7];
            unsigned u0 = xu[(size_t)r0 * 64 + lane];
            unsigned u1 = xu[(size_t)r1 * 64 + lane];
            unsigned u2 = xu[(size_t)r2 * 64 + lane];
            unsigned u3 = xu[(size_t)r3 * 64 + lane];
            unsigned u4 = xu[(size_t)r4 * 64 + lane];
            unsigned u5 = xu[(size_t)r5 * 64 + lane];
            unsigned u6 = xu[(size_t)r6 * 64 + lane];
            unsigned u7 = xu[(size_t)r7 * 64 + lane];
            ax += __uint_as_float(u0 << 16) + __uint_as_float(u1 << 16)
                + __uint_as_float(u2 << 16) + __uint_as_float(u3 << 16);
            ay += __uint_as_float(u0 & 0xffff0000u) + __uint_as_float(u1 & 0xffff0000u)
                + __uint_as_float(u2 & 0xffff0000u) + __uint_as_float(u3 & 0xffff0000u);
            ax += __uint_as_float(u4 << 16) + __uint_as_float(u5 << 16)
                + __uint_as_float(u6 << 16) + __uint_as_float(u7 << 16);
            ay += __uint_as_float(u4 & 0xffff0000u) + __uint_as_float(u5 & 0xffff0000u)
                + __uint_as_float(u6 & 0xffff0000u) + __uint_as_float(u7 & 0xffff0000u);
        }

        // remainder 1..7: one predicated batch, all loads issued together
        if (j < jend) {
            int last = jend - 1;
            int r[7];
#pragma unroll
            for (int k = 0; k < 7; ++k) {
                int jk = j + k;
                r[k] = srcs[jk < jend ? jk : last];  // clamped -> dup of last line (L1-hot)
            }
            unsigned u[7];
#pragma unroll
            for (int k = 0; k < 7; ++k) u[k] = xu[(size_t)r[k] * 64 + lane];
#pragma unroll
            for (int k = 0; k < 7; ++k) {
                unsigned uu = (j + k < jend) ? u[k] : 0u;  // +0.0f for invalid slots
                ax += __uint_as_float(uu << 16);
                ay += __uint_as_float(uu & 0xffff0000u);
            }
        }

        float ox = fmaf(ax, di, bb.x);
        float oy = fmaf(ay, di, bb.y);
        agg[(size_t)i * 64 + lane] = pack2_bf16(ox, oy);
        s.x += ox;
        s.y += oy;
        qq.x = fmaf(ox, ox, qq.x);
        qq.y = fmaf(oy, oy, qq.y);

        i = inext;
        e0 = ne0;
        e1 = ne1;
        di = ndi;
        uself = nself;
    }

    __shared__ float ssum[HIDDEN];
    __shared__ float ssq[HIDDEN];
    if (tid < HIDDEN) { ssum[tid] = 0.f; ssq[tid] = 0.f; }
    __syncthreads();
    atomicAdd(&ssum[2 * lane],     s.x);
    atomicAdd(&ssum[2 * lane + 1], s.y);
    atomicAdd(&ssq[2 * lane],      qq.x);
    atomicAdd(&ssq[2 * lane + 1],  qq.y);
    __syncthreads();
    if (tid < HIDDEN) {
        atomicAdd(&bn[tid],          ssum[tid]);
        atomicAdd(&bn[HIDDEN + tid], ssq[tid]);
    }
}

// ---------- K6: BN normalize + gamma/beta + ReLU: bf16 agg -> fp32 out ----------
__global__ __launch_bounds__(256) void k_apply(const unsigned* __restrict__ agg,
                                               float* __restrict__ out,
                                               const float* __restrict__ bn,
                                               const float* __restrict__ gamma,
                                               const float* __restrict__ beta,
                                               int total8, float invN) {
    __shared__ float sc[HIDDEN], sh[HIDDEN];
    int tid = threadIdx.x;
    if (tid < HIDDEN) {
        float mean = bn[tid] * invN;
        float var = bn[HIDDEN + tid] * invN - mean * mean;
        float inv = rsqrtf(var + BN_EPS);
        float g = gamma[tid] * inv;
        sc[tid] = g;
        sh[tid] = beta[tid] - mean * g;
    }
    __syncthreads();
    int idx = blockIdx.x * 256 + tid;  // one uint2 = 4 cols
    if (idx < total8) {
        uint2 u = ((const uint2*)agg)[idx];
        int c = (idx & 31) * 4;
        float4 v;
        v.x = __uint_as_float(u.x << 16);
        v.y = __uint_as_float(u.x & 0xffff0000u);
        v.z = __uint_as_float(u.y << 16);
        v.w = __uint_as_float(u.y & 0xffff0000u);
        v.x = fmaxf(fmaf(v.x, sc[c],     sh[c]),     0.f);
        v.y = fmaxf(fmaf(v.y, sc[c + 1], sh[c + 1]), 0.f);
        v.z = fmaxf(fmaf(v.z, sc[c + 2], sh[c + 2]), 0.f);
        v.w = fmaxf(fmaf(v.w, sc[c + 3], sh[c + 3]), 0.f);
        ((float4*)out)[idx] = v;
    }
}

extern "C" void kernel_launch(void* const* d_in, const int* in_sizes, int n_in,
                              void* d_out, int out_size, void* d_ws, size_t ws_size,
                              hipStream_t stream) {
    const float* x     = (const float*)d_in[0];
    const int*   edges = (const int*)d_in[1];   // [2, E] int32 (JAX x64-off)
    const float* W     = (const float*)d_in[2];
    const float* b     = (const float*)d_in[3];
    const float* gamma = (const float*)d_in[4];
    const float* beta  = (const float*)d_in[5];
    float* out = (float*)d_out;

    int N = in_sizes[0] / HIDDEN;
    int E = in_sizes[1] / 2;
    const int* row = edges;      // sources
    const int* col = edges + E;  // targets

    int NB = (N + SCAN_CHUNK - 1) / SCAN_CHUNK;

    // workspace carve (~58 MB). Zeroed region contiguous: cnt | flags | bn.
    char* p = (char*)d_ws;
    unsigned* xu  = (unsigned*)p; p += (size_t)N * 64 * sizeof(unsigned);  // xw bf16
    unsigned* agg = (unsigned*)p; p += (size_t)N * 64 * sizeof(unsigned);  // agg bf16
    float* dinv   = (float*)p; p += (size_t)N * sizeof(float);
    int*   cnt    = (int*)p;   p += (size_t)N * sizeof(int);               // zeroed
    unsigned long long* flags = (unsigned long long*)p;
    p += (size_t)NB * sizeof(unsigned long long);                          // zeroed
    float* bn     = (float*)p; p += 256 * sizeof(float);                   // zeroed
    int*   off    = (int*)p;   p += ((size_t)N + 4) * sizeof(int);
    int*   srcs   = (int*)p;   p += (size_t)E * sizeof(int);

    size_t zbytes = (size_t)N * sizeof(int) + (size_t)NB * sizeof(unsigned long long)
                  + 256 * sizeof(float);

    dim3 blk(256);
    hipMemsetAsync(cnt, 0, zbytes, stream);
    k_count<<<dim3((E + 1023) / 1024), blk, 0, stream>>>(col, cnt, E);
    k_csr<<<dim3(NB), blk, 0, stream>>>(cnt, flags, off, dinv, N, NB);
    k_gemm<<<dim3((N + 127) / 128), blk, 0, stream>>>(x, W, dinv, (unsigned short*)xu, N);
    k_place<<<dim3((E + 1023) / 1024), blk, 0, stream>>>(row, col, off, cnt, srcs, E);
    k_gather<<<dim3(2048), blk, 0, stream>>>(xu, dinv, off, srcs, b, agg, bn, N);
    int total8 = N * 32;  // uint2 groups (4 cols each)
    k_apply<<<dim3((total8 + 255) / 256), blk, 0, stream>>>(agg, out, bn, gamma, beta,
                                                            total8, 1.0f / (float)N);
}